// Round 8
// baseline (181.871 us; speedup 1.0000x reference)
//
#include <hip/hip_runtime.h>

#define N_NODES 50000
#define N_EDGES 1250000
#define DIM 64
#define NUM_CLASS 10
#define NUM_GRAPHS 256
#define CAP 64        // padded CSR row capacity (deg mean 25, sd 5; max deg << 64)
#define BSHIFT 6      // 64 nodes per bucket
#define NB ((N_NODES + 63) / 64)          // 782 buckets
#define BCAP 2048     // entries per bucket (mean ~1600, sd ~40; +11 sigma)
#define I4_TOTAL (N_EDGES / 4)            // 312500, exact
#define I4_PER_BLOCK 4096                 // 16384 edges/block -> ~21-entry chunks/bucket

// ---------------------------------------------------------------------------
// Phase A: bucket edges by dst>>6. Per-block LDS histogram -> one global
// atomicAdd per (block,bucket) chunk reservation -> dense packed writes.
// ---------------------------------------------------------------------------
__global__ __launch_bounds__(512) void bucket_kernel(
    const int4* __restrict__ src4, const int4* __restrict__ dst4,
    int* __restrict__ bcount, unsigned int* __restrict__ bdata)
{
    __shared__ int hist[NB];
    __shared__ int base[NB];
    const int tid = threadIdx.x;
    for (int k = tid; k < NB; k += 512) hist[k] = 0;
    __syncthreads();

    const int i4base = blockIdx.x * I4_PER_BLOCK;
    const int i4end = min(i4base + I4_PER_BLOCK, I4_TOTAL);

    for (int idx = i4base + tid; idx < i4end; idx += 512) {
        int4 d = dst4[idx];
        atomicAdd(&hist[d.x >> BSHIFT], 1);
        atomicAdd(&hist[d.y >> BSHIFT], 1);
        atomicAdd(&hist[d.z >> BSHIFT], 1);
        atomicAdd(&hist[d.w >> BSHIFT], 1);
    }
    __syncthreads();

    for (int k = tid; k < NB; k += 512) {
        int c = hist[k];
        base[k] = c ? atomicAdd(&bcount[k], c) : 0;
        hist[k] = 0;   // reuse as local cursor
    }
    __syncthreads();

    for (int idx = i4base + tid; idx < i4end; idx += 512) {
        int4 s = src4[idx];   // L2-hit re-read
        int4 d = dst4[idx];
        int k, p;
        k = d.x >> BSHIFT; p = base[k] + atomicAdd(&hist[k], 1);
        if (p < BCAP) bdata[(size_t)k * BCAP + p] = ((unsigned)(d.x & 63) << 16) | (unsigned)s.x;
        k = d.y >> BSHIFT; p = base[k] + atomicAdd(&hist[k], 1);
        if (p < BCAP) bdata[(size_t)k * BCAP + p] = ((unsigned)(d.y & 63) << 16) | (unsigned)s.y;
        k = d.z >> BSHIFT; p = base[k] + atomicAdd(&hist[k], 1);
        if (p < BCAP) bdata[(size_t)k * BCAP + p] = ((unsigned)(d.z & 63) << 16) | (unsigned)s.z;
        k = d.w >> BSHIFT; p = base[k] + atomicAdd(&hist[k], 1);
        if (p < BCAP) bdata[(size_t)k * BCAP + p] = ((unsigned)(d.w & 63) << 16) | (unsigned)s.w;
    }
}

// ---------------------------------------------------------------------------
// Phase B: one block per bucket. Build 64 padded CSR rows in LDS (LDS
// atomics), stream out 8 KB sequentially, write deg.
// ---------------------------------------------------------------------------
__global__ __launch_bounds__(256) void csr_build_kernel(
    const int* __restrict__ bcount, const unsigned int* __restrict__ bdata,
    int* __restrict__ deg, unsigned short* __restrict__ csr)
{
    __shared__ unsigned short lcsr[64 * CAP];   // 8 KB
    __shared__ int ldeg[64];
    const int tid = threadIdx.x;
    const int bk = blockIdx.x;
    if (tid < 64) ldeg[tid] = 0;
    __syncthreads();

    const int cnt = min(bcount[bk], BCAP);
    for (int i = tid; i < cnt; i += 256) {
        unsigned int e = bdata[(size_t)bk * BCAP + i];
        int d = (int)(e >> 16);
        int p = atomicAdd(&ldeg[d], 1);
        if (p < CAP) lcsr[d * CAP + p] = (unsigned short)(e & 0xffff);
    }
    __syncthreads();

    const int node0 = bk << BSHIFT;
    const int nlocal = min(64, N_NODES - node0);
    uint4* csr16 = (uint4*)(csr + (size_t)node0 * CAP);
    const uint4* l16 = (const uint4*)lcsr;
    for (int i = tid; i < nlocal * 8; i += 256) csr16[i] = l16[i];
    if (tid < nlocal) deg[node0 + tid] = ldeg[tid];
}

// ---------------------------------------------------------------------------
// Fused SAGE layer, phase-split per block (256 threads, 32 nodes):
//  Phase 1 (gather): 16-lane groups pull-aggregate 2 nodes each (8 gathers
//    in flight), write h rows TRANSPOSED into hT[128][33] (2-way banks, free).
//  Phase 2 (GEMM): out[32][64] = hT^T @ W. Lane (i=tid&15, j=tid>>4) owns
//    rows {i,i+16} x cols {4j..4j+3}. Per k: 2 broadcast ds_read_b32 (h) +
//    1 four-distinct ds_read_b128 (W) ~= 15 cyc vs 16 cyc VALU -> VALU-bound.
//  W reads amortized over 32 nodes/block (was 4/wave in R7: ~8x less DS).
//  LDS = 32 KB Wlds + 16.9 KB hT = 49.6 KB -> 3 blocks/CU.
// ---------------------------------------------------------------------------
__global__ __launch_bounds__(256) void sage_layer_kernel(
    const float4* __restrict__ x4,
    const int* __restrict__ deg,
    const unsigned short* __restrict__ csr,
    const float* __restrict__ W,    // [128*64]
    const float* __restrict__ b,    // [64]
    float4* __restrict__ out4)
{
    __shared__ float Wlds[128 * 64];
    __shared__ float hT[128][33];

    const int tid = threadIdx.x;
    for (int i = tid; i < 128 * 64 / 4; i += 256) {
        ((float4*)Wlds)[i] = ((const float4*)W)[i];
    }

    const int g = tid >> 4;     // gather group 0..15
    const int c = tid & 15;     // float4 column 0..15
    const int n0 = blockIdx.x * 32;

    // ---- Phase 1: gather-aggregate, 2 nodes per group ----
    #pragma unroll
    for (int p = 0; p < 2; ++p) {
        const int nl = g + p * 16;      // local node 0..31
        const int n = n0 + nl;
        float4 xv = make_float4(0.f, 0.f, 0.f, 0.f);
        float4 aggv = make_float4(0.f, 0.f, 0.f, 0.f);
        if (n < N_NODES) {
            xv = x4[(size_t)n * 16 + c];
            const int dcount = min(deg[n], CAP);
            const unsigned short* row = csr + (size_t)n * CAP;
            int j = 0;
            for (; j + 8 <= dcount; j += 8) {
                ushort4 sa = *(const ushort4*)(row + j);
                ushort4 sb = *(const ushort4*)(row + j + 4);
                float4 v0 = x4[(size_t)sa.x * 16 + c];
                float4 v1 = x4[(size_t)sa.y * 16 + c];
                float4 v2 = x4[(size_t)sa.z * 16 + c];
                float4 v3 = x4[(size_t)sa.w * 16 + c];
                float4 v4 = x4[(size_t)sb.x * 16 + c];
                float4 v5 = x4[(size_t)sb.y * 16 + c];
                float4 v6 = x4[(size_t)sb.z * 16 + c];
                float4 v7 = x4[(size_t)sb.w * 16 + c];
                aggv.x += (v0.x + v1.x) + (v2.x + v3.x) + (v4.x + v5.x) + (v6.x + v7.x);
                aggv.y += (v0.y + v1.y) + (v2.y + v3.y) + (v4.y + v5.y) + (v6.y + v7.y);
                aggv.z += (v0.z + v1.z) + (v2.z + v3.z) + (v4.z + v5.z) + (v6.z + v7.z);
                aggv.w += (v0.w + v1.w) + (v2.w + v3.w) + (v4.w + v5.w) + (v6.w + v7.w);
            }
            for (; j + 4 <= dcount; j += 4) {
                ushort4 sa = *(const ushort4*)(row + j);
                float4 v0 = x4[(size_t)sa.x * 16 + c];
                float4 v1 = x4[(size_t)sa.y * 16 + c];
                float4 v2 = x4[(size_t)sa.z * 16 + c];
                float4 v3 = x4[(size_t)sa.w * 16 + c];
                aggv.x += (v0.x + v1.x) + (v2.x + v3.x);
                aggv.y += (v0.y + v1.y) + (v2.y + v3.y);
                aggv.z += (v0.z + v1.z) + (v2.z + v3.z);
                aggv.w += (v0.w + v1.w) + (v2.w + v3.w);
            }
            for (; j < dcount; ++j) {
                int s = row[j];
                float4 v = x4[(size_t)s * 16 + c];
                aggv.x += v.x; aggv.y += v.y; aggv.z += v.z; aggv.w += v.w;
            }
        }
        // transposed store: h[0:64]=x, h[64:128]=agg (zeros for tail nodes)
        hT[4 * c + 0][nl] = xv.x;
        hT[4 * c + 1][nl] = xv.y;
        hT[4 * c + 2][nl] = xv.z;
        hT[4 * c + 3][nl] = xv.w;
        hT[64 + 4 * c + 0][nl] = aggv.x;
        hT[64 + 4 * c + 1][nl] = aggv.y;
        hT[64 + 4 * c + 2][nl] = aggv.z;
        hT[64 + 4 * c + 3][nl] = aggv.w;
    }
    __syncthreads();

    // ---- Phase 2: register-tiled GEMM out[32][64] ----
    const int i = tid & 15;     // row pair {i, i+16}
    const int j = tid >> 4;     // col quad 4j..4j+3
    const float4 bias = ((const float4*)b)[j];
    float4 a0 = bias, a1 = bias;
    #pragma unroll 8
    for (int k = 0; k < 128; ++k) {
        float h0 = hT[k][i];
        float h1 = hT[k][i + 16];
        float4 w4 = *(const float4*)(&Wlds[k * 64 + 4 * j]);
        a0.x += h0 * w4.x; a0.y += h0 * w4.y; a0.z += h0 * w4.z; a0.w += h0 * w4.w;
        a1.x += h1 * w4.x; a1.y += h1 * w4.y; a1.z += h1 * w4.z; a1.w += h1 * w4.w;
    }
    a0.x = fmaxf(a0.x, 0.f); a0.y = fmaxf(a0.y, 0.f);
    a0.z = fmaxf(a0.z, 0.f); a0.w = fmaxf(a0.w, 0.f);
    a1.x = fmaxf(a1.x, 0.f); a1.y = fmaxf(a1.y, 0.f);
    a1.z = fmaxf(a1.z, 0.f); a1.w = fmaxf(a1.w, 0.f);

    const int r0 = n0 + i;
    const int r1 = n0 + i + 16;
    if (r0 < N_NODES) out4[(size_t)r0 * 16 + j] = a0;
    if (r1 < N_NODES) out4[(size_t)r1 * 16 + j] = a1;
}

// ---------------------------------------------------------------------------
// Per-graph readout: batch sorted -> binary-search range, direct reduction,
// fused MLP + softmax. One 256-thread block per graph.
// ---------------------------------------------------------------------------
__global__ __launch_bounds__(256) void readout_kernel(
    const float* __restrict__ x,      // [N,64]
    const int* __restrict__ batch,    // [N], sorted
    const float* __restrict__ Wd1,    // [64][64]
    const float* __restrict__ bd1,    // [64]
    const float* __restrict__ Wd2,    // [64][10]
    const float* __restrict__ bd2,    // [10]
    float* __restrict__ out)          // [256][10]
{
    __shared__ float part[4][64];
    __shared__ float grow[64];
    __shared__ float h1[64];
    __shared__ float logits[NUM_CLASS];

    const int g = blockIdx.x;
    const int tid = threadIdx.x;
    const int d = tid & 63;
    const int r = tid >> 6;   // 0..3

    int lo = 0, hi = N_NODES;
    while (lo < hi) { int mid = (lo + hi) >> 1; if (batch[mid] < g) lo = mid + 1; else hi = mid; }
    const int start = lo;
    hi = N_NODES;
    while (lo < hi) { int mid = (lo + hi) >> 1; if (batch[mid] < g + 1) lo = mid + 1; else hi = mid; }
    const int end = lo;

    float acc = 0.f;
    for (int n = start + r; n < end; n += 4) acc += x[(size_t)n * 64 + d];
    part[r][d] = acc;
    __syncthreads();

    if (tid < 64) {
        grow[d] = part[0][d] + part[1][d] + part[2][d] + part[3][d];
    }
    __syncthreads();

    if (tid < 64) {
        float a = bd1[d];
        #pragma unroll 8
        for (int k = 0; k < 64; ++k) a += grow[k] * Wd1[k * 64 + d];
        h1[d] = fmaxf(a, 0.f);
    }
    __syncthreads();

    if (tid < NUM_CLASS) {
        float a = bd2[tid];
        #pragma unroll 8
        for (int k = 0; k < 64; ++k) a += h1[k] * Wd2[k * 10 + tid];
        logits[tid] = a;
    }
    __syncthreads();

    if (tid < NUM_CLASS) {
        float m = logits[0];
        #pragma unroll
        for (int i = 1; i < NUM_CLASS; ++i) m = fmaxf(m, logits[i]);
        float s = 0.f;
        #pragma unroll
        for (int i = 0; i < NUM_CLASS; ++i) s += expf(logits[i] - m);
        out[g * NUM_CLASS + tid] = expf(logits[tid] - m) / s;
    }
}

extern "C" void kernel_launch(void* const* d_in, const int* in_sizes, int n_in,
                              void* d_out, int out_size, void* d_ws, size_t ws_size,
                              hipStream_t stream) {
    const float* x0   = (const float*)d_in[0];
    const int*   edge = (const int*)d_in[1];
    const int*   batch= (const int*)d_in[2];
    const float* W1   = (const float*)d_in[3];
    const float* b1   = (const float*)d_in[4];
    const float* W2   = (const float*)d_in[5];
    const float* b2   = (const float*)d_in[6];
    const float* Wd1  = (const float*)d_in[7];
    const float* bd1  = (const float*)d_in[8];
    const float* Wd2  = (const float*)d_in[9];
    const float* bd2  = (const float*)d_in[10];
    float* out = (float*)d_out;

    const int* src = edge;             // edge_index[0]
    const int* dst = edge + N_EDGES;   // edge_index[1]

    const size_t nodeBytes = (size_t)N_NODES * DIM * sizeof(float);
    char* ws = (char*)d_ws;
    float* B   = (float*)ws;            ws += nodeBytes;                 // x1
    float* C   = (float*)ws;            ws += nodeBytes;                 // x2
    int*   deg = (int*)ws;              ws += N_NODES * 4;
    unsigned short* csr = (unsigned short*)ws; ws += (size_t)N_NODES * CAP * 2;
    int*   bcount = (int*)ws;           ws += NB * 4;
    // bucket_data aliases C: only live before the layers run (stream-ordered)
    unsigned int* bdata = (unsigned int*)C;   // NB*BCAP*4 = 6.4 MB <= 12.8 MB

    const int bucketBlocks = (I4_TOTAL + I4_PER_BLOCK - 1) / I4_PER_BLOCK;  // 77
    const int nodeBlocks = (N_NODES + 31) / 32;                              // 1563

    // Bucketed CSR build (by dst) — reused by both layers
    hipMemsetAsync(bcount, 0, NB * sizeof(int), stream);
    bucket_kernel<<<bucketBlocks, 512, 0, stream>>>(
        (const int4*)src, (const int4*)dst, bcount, bdata);
    csr_build_kernel<<<NB, 256, 0, stream>>>(bcount, bdata, deg, csr);

    // Two fused SAGE layers (pull-gather + transposed-LDS GEMM + relu)
    sage_layer_kernel<<<nodeBlocks, 256, 0, stream>>>(
        (const float4*)x0, deg, csr, W1, b1, (float4*)B);
    sage_layer_kernel<<<nodeBlocks, 256, 0, stream>>>(
        (const float4*)B, deg, csr, W2, b2, (float4*)C);

    // Readout + MLP + softmax
    readout_kernel<<<NUM_GRAPHS, 256, 0, stream>>>(
        C, batch, Wd1, bd1, Wd2, bd2, out);
}

// Round 9
// 150.327 us; speedup vs baseline: 1.2098x; 1.2098x over previous
//
#include <hip/hip_runtime.h>

#define N_NODES 50000
#define N_EDGES 1250000
#define DIM 64
#define NUM_CLASS 10
#define NUM_GRAPHS 256
#define CAP 64        // padded CSR row capacity (deg mean 25, sd 5; max deg << 64)
#define BSHIFT 6      // 64 nodes per bucket
#define NB ((N_NODES + 63) / 64)          // 782 buckets
#define BCAP 2048     // entries per bucket (mean ~1600, sd ~40; +11 sigma)
#define I4_TOTAL (N_EDGES / 4)            // 312500, exact
#define I4_PER_BLOCK 4096                 // 16384 edges/block -> ~21-entry chunks/bucket

typedef __attribute__((ext_vector_type(8))) short short8v;   // 8 bf16 = 4 VGPR
typedef __attribute__((ext_vector_type(4))) float float4v;   // MFMA C/D

// ---------------------------------------------------------------------------
// Phase A: bucket edges by dst>>6 (LDS histogram -> chunked dense writes).
// ---------------------------------------------------------------------------
__global__ __launch_bounds__(512) void bucket_kernel(
    const int4* __restrict__ src4, const int4* __restrict__ dst4,
    int* __restrict__ bcount, unsigned int* __restrict__ bdata)
{
    __shared__ int hist[NB];
    __shared__ int base[NB];
    const int tid = threadIdx.x;
    for (int k = tid; k < NB; k += 512) hist[k] = 0;
    __syncthreads();

    const int i4base = blockIdx.x * I4_PER_BLOCK;
    const int i4end = min(i4base + I4_PER_BLOCK, I4_TOTAL);

    for (int idx = i4base + tid; idx < i4end; idx += 512) {
        int4 d = dst4[idx];
        atomicAdd(&hist[d.x >> BSHIFT], 1);
        atomicAdd(&hist[d.y >> BSHIFT], 1);
        atomicAdd(&hist[d.z >> BSHIFT], 1);
        atomicAdd(&hist[d.w >> BSHIFT], 1);
    }
    __syncthreads();

    for (int k = tid; k < NB; k += 512) {
        int c = hist[k];
        base[k] = c ? atomicAdd(&bcount[k], c) : 0;
        hist[k] = 0;   // reuse as local cursor
    }
    __syncthreads();

    for (int idx = i4base + tid; idx < i4end; idx += 512) {
        int4 s = src4[idx];   // L2-hit re-read
        int4 d = dst4[idx];
        int k, p;
        k = d.x >> BSHIFT; p = base[k] + atomicAdd(&hist[k], 1);
        if (p < BCAP) bdata[(size_t)k * BCAP + p] = ((unsigned)(d.x & 63) << 16) | (unsigned)s.x;
        k = d.y >> BSHIFT; p = base[k] + atomicAdd(&hist[k], 1);
        if (p < BCAP) bdata[(size_t)k * BCAP + p] = ((unsigned)(d.y & 63) << 16) | (unsigned)s.y;
        k = d.z >> BSHIFT; p = base[k] + atomicAdd(&hist[k], 1);
        if (p < BCAP) bdata[(size_t)k * BCAP + p] = ((unsigned)(d.z & 63) << 16) | (unsigned)s.z;
        k = d.w >> BSHIFT; p = base[k] + atomicAdd(&hist[k], 1);
        if (p < BCAP) bdata[(size_t)k * BCAP + p] = ((unsigned)(d.w & 63) << 16) | (unsigned)s.w;
    }
}

// ---------------------------------------------------------------------------
// Phase B: one block per bucket. Build 64 padded CSR rows in LDS, stream out.
// ---------------------------------------------------------------------------
__global__ __launch_bounds__(256) void csr_build_kernel(
    const int* __restrict__ bcount, const unsigned int* __restrict__ bdata,
    int* __restrict__ deg, unsigned short* __restrict__ csr)
{
    __shared__ unsigned short lcsr[64 * CAP];   // 8 KB
    __shared__ int ldeg[64];
    const int tid = threadIdx.x;
    const int bk = blockIdx.x;
    if (tid < 64) ldeg[tid] = 0;
    __syncthreads();

    const int cnt = min(bcount[bk], BCAP);
    for (int i = tid; i < cnt; i += 256) {
        unsigned int e = bdata[(size_t)bk * BCAP + i];
        int d = (int)(e >> 16);
        int p = atomicAdd(&ldeg[d], 1);
        if (p < CAP) lcsr[d * CAP + p] = (unsigned short)(e & 0xffff);
    }
    __syncthreads();

    const int node0 = bk << BSHIFT;
    const int nlocal = min(64, N_NODES - node0);
    uint4* csr16 = (uint4*)(csr + (size_t)node0 * CAP);
    const uint4* l16 = (const uint4*)lcsr;
    for (int i = tid; i < nlocal * 8; i += 256) csr16[i] = l16[i];
    if (tid < nlocal) deg[node0 + tid] = ldeg[tid];
}

// ---------------------------------------------------------------------------
// Pack W1,W2 into MFMA B-fragment layout (bf16 hi/lo split), once per call.
// Element t = [layer][kt][ct][h][lane][i]; value = split(W[k][col], h) with
// k = kt*32 + (lane>>4)*8 + i, col = ct*16 + (lane&15).
// ---------------------------------------------------------------------------
__global__ __launch_bounds__(256) void pack_w_kernel(
    const float* __restrict__ W1, const float* __restrict__ W2,
    unsigned short* __restrict__ WB)
{
    int t = blockIdx.x * 256 + threadIdx.x;       // 0..32767
    int layer = t >> 14;
    int r = t & 16383;
    int i    = r & 7;
    int lane = (r >> 3) & 63;
    int h    = (r >> 9) & 1;
    int ct   = (r >> 10) & 3;
    int kt   = (r >> 12) & 3;
    int k   = kt * 32 + (lane >> 4) * 8 + i;
    int col = ct * 16 + (lane & 15);
    const float* W = layer ? W2 : W1;
    float x = W[k * 64 + col];
    unsigned bits = __float_as_uint(x);
    unsigned short u;
    if (h == 0) {
        u = (unsigned short)(bits >> 16);                       // hi (truncate)
    } else {
        float y = x - __uint_as_float(bits & 0xffff0000u);      // residual
        u = (unsigned short)(__float_as_uint(y) >> 16);         // lo
    }
    WB[t] = u;
}

// ---------------------------------------------------------------------------
// Fused SAGE layer: gather phase (R6-proven, 16 groups x 2 nodes, 8 gathers
// in flight) writes h transposed into hT[128][33]; then MFMA GEMM:
// out[32][64] = h[32][128] @ W via 16x16x32 bf16 MFMA, 3-term hi/lo emu
// (rel err ~5e-5; outputs are saturated softmax so huge margin).
// B-frags read from global WB (L2-resident 32KB). LDS = hT only (16.5KB)
// -> 8 blocks/CU for gather latency hiding. Wave w: rows (w>>1)*16..+15,
// cols ((w&1)*2 + {0,1})*16..+15. D layout (m89-verified): col=lane&15,
// row=(lane>>4)*4+reg.
// ---------------------------------------------------------------------------
__global__ __launch_bounds__(256) void sage_layer_kernel(
    const float4* __restrict__ x4,
    const int* __restrict__ deg,
    const unsigned short* __restrict__ csr,
    const unsigned short* __restrict__ WB,   // packed B-frags (this layer)
    const float* __restrict__ b,             // [64]
    float* __restrict__ out)                 // [N][64]
{
    __shared__ float hT[128][33];

    const int tid = threadIdx.x;
    const int g = tid >> 4;     // gather group 0..15
    const int c = tid & 15;     // float4 column 0..15
    const int n0 = blockIdx.x * 32;

    // ---- Phase 1: gather-aggregate, 2 nodes per group ----
    #pragma unroll
    for (int p = 0; p < 2; ++p) {
        const int nl = g + p * 16;      // local node 0..31
        const int n = n0 + nl;
        float4 xv = make_float4(0.f, 0.f, 0.f, 0.f);
        float4 aggv = make_float4(0.f, 0.f, 0.f, 0.f);
        if (n < N_NODES) {
            xv = x4[(size_t)n * 16 + c];
            const int dcount = min(deg[n], CAP);
            const unsigned short* row = csr + (size_t)n * CAP;
            int j = 0;
            for (; j + 8 <= dcount; j += 8) {
                ushort4 sa = *(const ushort4*)(row + j);
                ushort4 sb = *(const ushort4*)(row + j + 4);
                float4 v0 = x4[(size_t)sa.x * 16 + c];
                float4 v1 = x4[(size_t)sa.y * 16 + c];
                float4 v2 = x4[(size_t)sa.z * 16 + c];
                float4 v3 = x4[(size_t)sa.w * 16 + c];
                float4 v4 = x4[(size_t)sb.x * 16 + c];
                float4 v5 = x4[(size_t)sb.y * 16 + c];
                float4 v6 = x4[(size_t)sb.z * 16 + c];
                float4 v7 = x4[(size_t)sb.w * 16 + c];
                aggv.x += (v0.x + v1.x) + (v2.x + v3.x) + (v4.x + v5.x) + (v6.x + v7.x);
                aggv.y += (v0.y + v1.y) + (v2.y + v3.y) + (v4.y + v5.y) + (v6.y + v7.y);
                aggv.z += (v0.z + v1.z) + (v2.z + v3.z) + (v4.z + v5.z) + (v6.z + v7.z);
                aggv.w += (v0.w + v1.w) + (v2.w + v3.w) + (v4.w + v5.w) + (v6.w + v7.w);
            }
            for (; j + 4 <= dcount; j += 4) {
                ushort4 sa = *(const ushort4*)(row + j);
                float4 v0 = x4[(size_t)sa.x * 16 + c];
                float4 v1 = x4[(size_t)sa.y * 16 + c];
                float4 v2 = x4[(size_t)sa.z * 16 + c];
                float4 v3 = x4[(size_t)sa.w * 16 + c];
                aggv.x += (v0.x + v1.x) + (v2.x + v3.x);
                aggv.y += (v0.y + v1.y) + (v2.y + v3.y);
                aggv.z += (v0.z + v1.z) + (v2.z + v3.z);
                aggv.w += (v0.w + v1.w) + (v2.w + v3.w);
            }
            for (; j < dcount; ++j) {
                int s = row[j];
                float4 v = x4[(size_t)s * 16 + c];
                aggv.x += v.x; aggv.y += v.y; aggv.z += v.z; aggv.w += v.w;
            }
        }
        // transposed store (zeros for tail nodes): h[0:64]=x, h[64:128]=agg
        hT[4 * c + 0][nl] = xv.x;
        hT[4 * c + 1][nl] = xv.y;
        hT[4 * c + 2][nl] = xv.z;
        hT[4 * c + 3][nl] = xv.w;
        hT[64 + 4 * c + 0][nl] = aggv.x;
        hT[64 + 4 * c + 1][nl] = aggv.y;
        hT[64 + 4 * c + 2][nl] = aggv.z;
        hT[64 + 4 * c + 3][nl] = aggv.w;
    }
    __syncthreads();

    // ---- Phase 2: MFMA GEMM ----
    const int lane = tid & 63;
    const int wid  = tid >> 6;      // 0..3
    const int rt   = wid >> 1;      // row-tile 0..1
    const int ct0  = (wid & 1) * 2; // col-tiles ct0, ct0+1
    const int r  = lane & 15;
    const int q  = lane >> 4;

    const int col0 = (ct0 + 0) * 16 + r;
    const int col1 = (ct0 + 1) * 16 + r;
    const float bv0 = b[col0];
    const float bv1 = b[col1];
    float4v acc0 = {bv0, bv0, bv0, bv0};
    float4v acc1 = {bv1, bv1, bv1, bv1};

    #pragma unroll
    for (int kt = 0; kt < 4; ++kt) {
        // A fragment: row = rt*16 + r, k = kt*32 + q*8 + i  (f32 -> hi/lo bf16)
        short8v a_hi, a_lo;
        #pragma unroll
        for (int i = 0; i < 8; ++i) {
            float av = hT[kt * 32 + q * 8 + i][rt * 16 + r];
            unsigned bits = __float_as_uint(av);
            a_hi[i] = (short)(bits >> 16);
            float y = av - __uint_as_float(bits & 0xffff0000u);
            a_lo[i] = (short)(__float_as_uint(y) >> 16);
        }
        // B fragments from global (L2-hit): [kt][ct][h][lane][8]
        const unsigned short* Wk = WB + kt * 4096;
        const short8v bh0 = *(const short8v*)(Wk + (ct0 + 0) * 1024 + 0 * 512 + lane * 8);
        const short8v bl0 = *(const short8v*)(Wk + (ct0 + 0) * 1024 + 1 * 512 + lane * 8);
        const short8v bh1 = *(const short8v*)(Wk + (ct0 + 1) * 1024 + 0 * 512 + lane * 8);
        const short8v bl1 = *(const short8v*)(Wk + (ct0 + 1) * 1024 + 1 * 512 + lane * 8);

        acc0 = __builtin_amdgcn_mfma_f32_16x16x32_bf16(a_hi, bh0, acc0, 0, 0, 0);
        acc0 = __builtin_amdgcn_mfma_f32_16x16x32_bf16(a_hi, bl0, acc0, 0, 0, 0);
        acc0 = __builtin_amdgcn_mfma_f32_16x16x32_bf16(a_lo, bh0, acc0, 0, 0, 0);
        acc1 = __builtin_amdgcn_mfma_f32_16x16x32_bf16(a_hi, bh1, acc1, 0, 0, 0);
        acc1 = __builtin_amdgcn_mfma_f32_16x16x32_bf16(a_hi, bl1, acc1, 0, 0, 0);
        acc1 = __builtin_amdgcn_mfma_f32_16x16x32_bf16(a_lo, bh1, acc1, 0, 0, 0);
    }

    // Epilogue: D row = rt*16 + q*4 + reg, col = ct*16 + r; relu + store
    #pragma unroll
    for (int reg = 0; reg < 4; ++reg) {
        int n = n0 + rt * 16 + q * 4 + reg;
        if (n < N_NODES) {
            out[(size_t)n * 64 + col0] = fmaxf(acc0[reg], 0.f);
            out[(size_t)n * 64 + col1] = fmaxf(acc1[reg], 0.f);
        }
    }
}

// ---------------------------------------------------------------------------
// Per-graph readout: batch sorted -> binary-search range, direct reduction,
// fused MLP + softmax. One 256-thread block per graph.
// ---------------------------------------------------------------------------
__global__ __launch_bounds__(256) void readout_kernel(
    const float* __restrict__ x,      // [N,64]
    const int* __restrict__ batch,    // [N], sorted
    const float* __restrict__ Wd1,    // [64][64]
    const float* __restrict__ bd1,    // [64]
    const float* __restrict__ Wd2,    // [64][10]
    const float* __restrict__ bd2,    // [10]
    float* __restrict__ out)          // [256][10]
{
    __shared__ float part[4][64];
    __shared__ float grow[64];
    __shared__ float h1[64];
    __shared__ float logits[NUM_CLASS];

    const int g = blockIdx.x;
    const int tid = threadIdx.x;
    const int d = tid & 63;
    const int r = tid >> 6;   // 0..3

    int lo = 0, hi = N_NODES;
    while (lo < hi) { int mid = (lo + hi) >> 1; if (batch[mid] < g) lo = mid + 1; else hi = mid; }
    const int start = lo;
    hi = N_NODES;
    while (lo < hi) { int mid = (lo + hi) >> 1; if (batch[mid] < g + 1) lo = mid + 1; else hi = mid; }
    const int end = lo;

    float acc = 0.f;
    for (int n = start + r; n < end; n += 4) acc += x[(size_t)n * 64 + d];
    part[r][d] = acc;
    __syncthreads();

    if (tid < 64) {
        grow[d] = part[0][d] + part[1][d] + part[2][d] + part[3][d];
    }
    __syncthreads();

    if (tid < 64) {
        float a = bd1[d];
        #pragma unroll 8
        for (int k = 0; k < 64; ++k) a += grow[k] * Wd1[k * 64 + d];
        h1[d] = fmaxf(a, 0.f);
    }
    __syncthreads();

    if (tid < NUM_CLASS) {
        float a = bd2[tid];
        #pragma unroll 8
        for (int k = 0; k < 64; ++k) a += h1[k] * Wd2[k * 10 + tid];
        logits[tid] = a;
    }
    __syncthreads();

    if (tid < NUM_CLASS) {
        float m = logits[0];
        #pragma unroll
        for (int i = 1; i < NUM_CLASS; ++i) m = fmaxf(m, logits[i]);
        float s = 0.f;
        #pragma unroll
        for (int i = 0; i < NUM_CLASS; ++i) s += expf(logits[i] - m);
        out[g * NUM_CLASS + tid] = expf(logits[tid] - m) / s;
    }
}

extern "C" void kernel_launch(void* const* d_in, const int* in_sizes, int n_in,
                              void* d_out, int out_size, void* d_ws, size_t ws_size,
                              hipStream_t stream) {
    const float* x0   = (const float*)d_in[0];
    const int*   edge = (const int*)d_in[1];
    const int*   batch= (const int*)d_in[2];
    const float* W1   = (const float*)d_in[3];
    const float* b1   = (const float*)d_in[4];
    const float* W2   = (const float*)d_in[5];
    const float* b2   = (const float*)d_in[6];
    const float* Wd1  = (const float*)d_in[7];
    const float* bd1  = (const float*)d_in[8];
    const float* Wd2  = (const float*)d_in[9];
    const float* bd2  = (const float*)d_in[10];
    float* out = (float*)d_out;

    const int* src = edge;             // edge_index[0]
    const int* dst = edge + N_EDGES;   // edge_index[1]

    const size_t nodeBytes = (size_t)N_NODES * DIM * sizeof(float);
    char* ws = (char*)d_ws;
    float* B   = (float*)ws;            ws += nodeBytes;                 // x1
    float* C   = (float*)ws;            ws += nodeBytes;                 // x2
    int*   deg = (int*)ws;              ws += N_NODES * 4;
    unsigned short* csr = (unsigned short*)ws; ws += (size_t)N_NODES * CAP * 2;
    int*   bcount = (int*)ws;           ws += NB * 4;
    unsigned short* WB = (unsigned short*)ws;  ws += 32768 * 2;          // 64KB packed W1+W2
    // bucket_data aliases C: only live before the layers run (stream-ordered)
    unsigned int* bdata = (unsigned int*)C;   // NB*BCAP*4 = 6.4 MB <= 12.8 MB

    const int bucketBlocks = (I4_TOTAL + I4_PER_BLOCK - 1) / I4_PER_BLOCK;  // 77
    const int nodeBlocks = (N_NODES + 31) / 32;                              // 1563

    // Bucketed CSR build (by dst) — reused by both layers
    hipMemsetAsync(bcount, 0, NB * sizeof(int), stream);
    bucket_kernel<<<bucketBlocks, 512, 0, stream>>>(
        (const int4*)src, (const int4*)dst, bcount, bdata);
    csr_build_kernel<<<NB, 256, 0, stream>>>(bcount, bdata, deg, csr);

    // Pack W1,W2 into MFMA B-frag layout (hi/lo bf16)
    pack_w_kernel<<<128, 256, 0, stream>>>(W1, W2, WB);

    // Two fused SAGE layers (pull-gather + MFMA GEMM + relu)
    sage_layer_kernel<<<nodeBlocks, 256, 0, stream>>>(
        (const float4*)x0, deg, csr, WB, b1, B);
    sage_layer_kernel<<<nodeBlocks, 256, 0, stream>>>(
        (const float4*)B, deg, csr, WB + 16384, b2, C);

    // Readout + MLP + softmax
    readout_kernel<<<NUM_GRAPHS, 256, 0, stream>>>(
        C, batch, Wd1, bd1, Wd2, bd2, out);
}

// Round 10
// 132.905 us; speedup vs baseline: 1.3684x; 1.1311x over previous
//
#include <hip/hip_runtime.h>

#define N_NODES 50000
#define N_EDGES 1250000
#define DIM 64
#define NUM_CLASS 10
#define NUM_GRAPHS 256
#define CAP 64        // padded CSR row capacity (deg mean 25, sd 5; max deg << 64)
#define BSHIFT 6      // 64 nodes per bucket
#define NB ((N_NODES + 63) / 64)          // 782 buckets
#define BCAP 2048     // entries per bucket (mean ~1600, sd ~40; +11 sigma)
#define I4_TOTAL (N_EDGES / 4)            // 312500, exact
#define I4_PER_BLOCK 4096                 // 16384 edges/block -> ~21-entry chunks/bucket

typedef __attribute__((ext_vector_type(8))) short short8v;   // 8 bf16 = 4 VGPR
typedef __attribute__((ext_vector_type(4))) float float4v;   // MFMA C/D

__device__ inline unsigned short f2bf_rne(float f) {
    unsigned b = __float_as_uint(f);
    return (unsigned short)((b + 0x7fff + ((b >> 16) & 1)) >> 16);
}

// ---------------------------------------------------------------------------
// Phase A: bucket edges by dst>>6 (LDS histogram -> chunked dense writes).
// ---------------------------------------------------------------------------
__global__ __launch_bounds__(512) void bucket_kernel(
    const int4* __restrict__ src4, const int4* __restrict__ dst4,
    int* __restrict__ bcount, unsigned int* __restrict__ bdata)
{
    __shared__ int hist[NB];
    __shared__ int base[NB];
    const int tid = threadIdx.x;
    for (int k = tid; k < NB; k += 512) hist[k] = 0;
    __syncthreads();

    const int i4base = blockIdx.x * I4_PER_BLOCK;
    const int i4end = min(i4base + I4_PER_BLOCK, I4_TOTAL);

    for (int idx = i4base + tid; idx < i4end; idx += 512) {
        int4 d = dst4[idx];
        atomicAdd(&hist[d.x >> BSHIFT], 1);
        atomicAdd(&hist[d.y >> BSHIFT], 1);
        atomicAdd(&hist[d.z >> BSHIFT], 1);
        atomicAdd(&hist[d.w >> BSHIFT], 1);
    }
    __syncthreads();

    for (int k = tid; k < NB; k += 512) {
        int c = hist[k];
        base[k] = c ? atomicAdd(&bcount[k], c) : 0;
        hist[k] = 0;   // reuse as local cursor
    }
    __syncthreads();

    for (int idx = i4base + tid; idx < i4end; idx += 512) {
        int4 s = src4[idx];   // L2-hit re-read
        int4 d = dst4[idx];
        int k, p;
        k = d.x >> BSHIFT; p = base[k] + atomicAdd(&hist[k], 1);
        if (p < BCAP) bdata[(size_t)k * BCAP + p] = ((unsigned)(d.x & 63) << 16) | (unsigned)s.x;
        k = d.y >> BSHIFT; p = base[k] + atomicAdd(&hist[k], 1);
        if (p < BCAP) bdata[(size_t)k * BCAP + p] = ((unsigned)(d.y & 63) << 16) | (unsigned)s.y;
        k = d.z >> BSHIFT; p = base[k] + atomicAdd(&hist[k], 1);
        if (p < BCAP) bdata[(size_t)k * BCAP + p] = ((unsigned)(d.z & 63) << 16) | (unsigned)s.z;
        k = d.w >> BSHIFT; p = base[k] + atomicAdd(&hist[k], 1);
        if (p < BCAP) bdata[(size_t)k * BCAP + p] = ((unsigned)(d.w & 63) << 16) | (unsigned)s.w;
    }
}

// ---------------------------------------------------------------------------
// Phase B: one block per bucket. Build 64 padded CSR rows in LDS, stream out.
// ---------------------------------------------------------------------------
__global__ __launch_bounds__(256) void csr_build_kernel(
    const int* __restrict__ bcount, const unsigned int* __restrict__ bdata,
    int* __restrict__ deg, unsigned short* __restrict__ csr)
{
    __shared__ unsigned short lcsr[64 * CAP];   // 8 KB
    __shared__ int ldeg[64];
    const int tid = threadIdx.x;
    const int bk = blockIdx.x;
    if (tid < 64) ldeg[tid] = 0;
    __syncthreads();

    const int cnt = min(bcount[bk], BCAP);
    for (int i = tid; i < cnt; i += 256) {
        unsigned int e = bdata[(size_t)bk * BCAP + i];
        int d = (int)(e >> 16);
        int p = atomicAdd(&ldeg[d], 1);
        if (p < CAP) lcsr[d * CAP + p] = (unsigned short)(e & 0xffff);
    }
    __syncthreads();

    const int node0 = bk << BSHIFT;
    const int nlocal = min(64, N_NODES - node0);
    uint4* csr16 = (uint4*)(csr + (size_t)node0 * CAP);
    const uint4* l16 = (const uint4*)lcsr;
    for (int i = tid; i < nlocal * 8; i += 256) csr16[i] = l16[i];
    if (tid < nlocal) deg[node0 + tid] = ldeg[tid];
}

// ---------------------------------------------------------------------------
// f32 [N][64] -> bf16 [N][64] (RNE). One float4 -> ushort4 per thread.
// ---------------------------------------------------------------------------
__global__ __launch_bounds__(256) void convert_kernel(
    const float4* __restrict__ x4, ushort4* __restrict__ xb4)
{
    int t = blockIdx.x * 256 + threadIdx.x;
    if (t < N_NODES * 16) {
        float4 v = x4[t];
        ushort4 u;
        u.x = f2bf_rne(v.x);
        u.y = f2bf_rne(v.y);
        u.z = f2bf_rne(v.z);
        u.w = f2bf_rne(v.w);
        xb4[t] = u;
    }
}

// ---------------------------------------------------------------------------
// Pack W1,W2 into MFMA B-fragment layout (bf16 hi/lo split), once per call.
// ---------------------------------------------------------------------------
__global__ __launch_bounds__(256) void pack_w_kernel(
    const float* __restrict__ W1, const float* __restrict__ W2,
    unsigned short* __restrict__ WB)
{
    int t = blockIdx.x * 256 + threadIdx.x;       // 0..32767
    int layer = t >> 14;
    int r = t & 16383;
    int i    = r & 7;
    int lane = (r >> 3) & 63;
    int h    = (r >> 9) & 1;
    int ct   = (r >> 10) & 3;
    int kt   = (r >> 12) & 3;
    int k   = kt * 32 + (lane >> 4) * 8 + i;
    int col = ct * 16 + (lane & 15);
    const float* W = layer ? W2 : W1;
    float x = W[k * 64 + col];
    unsigned bits = __float_as_uint(x);
    unsigned short u;
    if (h == 0) {
        u = (unsigned short)(bits >> 16);                       // hi (truncate)
    } else {
        float y = x - __uint_as_float(bits & 0xffff0000u);      // residual
        u = (unsigned short)(__float_as_uint(y) >> 16);         // lo
    }
    WB[t] = u;
}

// ---------------------------------------------------------------------------
// Fused SAGE layer: gather phase pulls neighbor rows from the BF16 copy
// (128 B/row = 2 lines, halves L2-miss traffic vs f32), accumulates f32,
// writes h transposed into hT[128][33]; self term stays f32. Then MFMA
// GEMM out[32][64] = h[32][128] @ W (16x16x32 bf16, 3-term hi/lo emu).
// Epilogue: relu -> f32 out (+ optional bf16 copy for the next layer).
// LDS = 16.5 KB. Wave w: rows (w>>1)*16..+15, cols ((w&1)*2+{0,1})*16..+15.
// D layout (m89-verified): col=lane&15, row=(lane>>4)*4+reg.
// ---------------------------------------------------------------------------
__global__ __launch_bounds__(256) void sage_layer_kernel(
    const float4* __restrict__ x4,           // f32 self features
    const ushort4* __restrict__ xb,          // bf16 gather features
    const int* __restrict__ deg,
    const unsigned short* __restrict__ csr,
    const unsigned short* __restrict__ WB,   // packed B-frags (this layer)
    const float* __restrict__ b,             // [64]
    float* __restrict__ out,                 // [N][64] f32
    unsigned short* __restrict__ outb)       // [N][64] bf16 or nullptr
{
    __shared__ float hT[128][33];

    const int tid = threadIdx.x;
    const int g = tid >> 4;     // gather group 0..15
    const int c = tid & 15;     // column quad 0..15 (elements 4c..4c+3)
    const int n0 = blockIdx.x * 32;

    // ---- Phase 1: gather-aggregate (bf16 rows), 2 nodes per group ----
    #pragma unroll
    for (int p = 0; p < 2; ++p) {
        const int nl = g + p * 16;      // local node 0..31
        const int n = n0 + nl;
        float4 xv = make_float4(0.f, 0.f, 0.f, 0.f);
        float4 aggv = make_float4(0.f, 0.f, 0.f, 0.f);
        if (n < N_NODES) {
            xv = x4[(size_t)n * 16 + c];
            const int dcount = min(deg[n], CAP);
            const unsigned short* row = csr + (size_t)n * CAP;
            int j = 0;
            for (; j + 8 <= dcount; j += 8) {
                ushort4 sa = *(const ushort4*)(row + j);
                ushort4 sb = *(const ushort4*)(row + j + 4);
                ushort4 q0 = xb[(size_t)sa.x * 16 + c];
                ushort4 q1 = xb[(size_t)sa.y * 16 + c];
                ushort4 q2 = xb[(size_t)sa.z * 16 + c];
                ushort4 q3 = xb[(size_t)sa.w * 16 + c];
                ushort4 q4 = xb[(size_t)sb.x * 16 + c];
                ushort4 q5 = xb[(size_t)sb.y * 16 + c];
                ushort4 q6 = xb[(size_t)sb.z * 16 + c];
                ushort4 q7 = xb[(size_t)sb.w * 16 + c];
                aggv.x += __uint_as_float((unsigned)q0.x << 16) + __uint_as_float((unsigned)q1.x << 16)
                        + __uint_as_float((unsigned)q2.x << 16) + __uint_as_float((unsigned)q3.x << 16)
                        + __uint_as_float((unsigned)q4.x << 16) + __uint_as_float((unsigned)q5.x << 16)
                        + __uint_as_float((unsigned)q6.x << 16) + __uint_as_float((unsigned)q7.x << 16);
                aggv.y += __uint_as_float((unsigned)q0.y << 16) + __uint_as_float((unsigned)q1.y << 16)
                        + __uint_as_float((unsigned)q2.y << 16) + __uint_as_float((unsigned)q3.y << 16)
                        + __uint_as_float((unsigned)q4.y << 16) + __uint_as_float((unsigned)q5.y << 16)
                        + __uint_as_float((unsigned)q6.y << 16) + __uint_as_float((unsigned)q7.y << 16);
                aggv.z += __uint_as_float((unsigned)q0.z << 16) + __uint_as_float((unsigned)q1.z << 16)
                        + __uint_as_float((unsigned)q2.z << 16) + __uint_as_float((unsigned)q3.z << 16)
                        + __uint_as_float((unsigned)q4.z << 16) + __uint_as_float((unsigned)q5.z << 16)
                        + __uint_as_float((unsigned)q6.z << 16) + __uint_as_float((unsigned)q7.z << 16);
                aggv.w += __uint_as_float((unsigned)q0.w << 16) + __uint_as_float((unsigned)q1.w << 16)
                        + __uint_as_float((unsigned)q2.w << 16) + __uint_as_float((unsigned)q3.w << 16)
                        + __uint_as_float((unsigned)q4.w << 16) + __uint_as_float((unsigned)q5.w << 16)
                        + __uint_as_float((unsigned)q6.w << 16) + __uint_as_float((unsigned)q7.w << 16);
            }
            for (; j < dcount; ++j) {
                int s = row[j];
                ushort4 q = xb[(size_t)s * 16 + c];
                aggv.x += __uint_as_float((unsigned)q.x << 16);
                aggv.y += __uint_as_float((unsigned)q.y << 16);
                aggv.z += __uint_as_float((unsigned)q.z << 16);
                aggv.w += __uint_as_float((unsigned)q.w << 16);
            }
        }
        // transposed store (zeros for tail nodes): h[0:64]=x, h[64:128]=agg
        hT[4 * c + 0][nl] = xv.x;
        hT[4 * c + 1][nl] = xv.y;
        hT[4 * c + 2][nl] = xv.z;
        hT[4 * c + 3][nl] = xv.w;
        hT[64 + 4 * c + 0][nl] = aggv.x;
        hT[64 + 4 * c + 1][nl] = aggv.y;
        hT[64 + 4 * c + 2][nl] = aggv.z;
        hT[64 + 4 * c + 3][nl] = aggv.w;
    }
    __syncthreads();

    // ---- Phase 2: MFMA GEMM ----
    const int lane = tid & 63;
    const int wid  = tid >> 6;      // 0..3
    const int rt   = wid >> 1;      // row-tile 0..1
    const int ct0  = (wid & 1) * 2; // col-tiles ct0, ct0+1
    const int r  = lane & 15;
    const int q  = lane >> 4;

    const int col0 = (ct0 + 0) * 16 + r;
    const int col1 = (ct0 + 1) * 16 + r;
    const float bv0 = b[col0];
    const float bv1 = b[col1];
    float4v acc0 = {bv0, bv0, bv0, bv0};
    float4v acc1 = {bv1, bv1, bv1, bv1};

    #pragma unroll
    for (int kt = 0; kt < 4; ++kt) {
        short8v a_hi, a_lo;
        #pragma unroll
        for (int i = 0; i < 8; ++i) {
            float av = hT[kt * 32 + q * 8 + i][rt * 16 + r];
            unsigned bits = __float_as_uint(av);
            a_hi[i] = (short)(bits >> 16);
            float y = av - __uint_as_float(bits & 0xffff0000u);
            a_lo[i] = (short)(__float_as_uint(y) >> 16);
        }
        const unsigned short* Wk = WB + kt * 4096;
        const short8v bh0 = *(const short8v*)(Wk + (ct0 + 0) * 1024 + 0 * 512 + lane * 8);
        const short8v bl0 = *(const short8v*)(Wk + (ct0 + 0) * 1024 + 1 * 512 + lane * 8);
        const short8v bh1 = *(const short8v*)(Wk + (ct0 + 1) * 1024 + 0 * 512 + lane * 8);
        const short8v bl1 = *(const short8v*)(Wk + (ct0 + 1) * 1024 + 1 * 512 + lane * 8);

        acc0 = __builtin_amdgcn_mfma_f32_16x16x32_bf16(a_hi, bh0, acc0, 0, 0, 0);
        acc0 = __builtin_amdgcn_mfma_f32_16x16x32_bf16(a_hi, bl0, acc0, 0, 0, 0);
        acc0 = __builtin_amdgcn_mfma_f32_16x16x32_bf16(a_lo, bh0, acc0, 0, 0, 0);
        acc1 = __builtin_amdgcn_mfma_f32_16x16x32_bf16(a_hi, bh1, acc1, 0, 0, 0);
        acc1 = __builtin_amdgcn_mfma_f32_16x16x32_bf16(a_hi, bl1, acc1, 0, 0, 0);
        acc1 = __builtin_amdgcn_mfma_f32_16x16x32_bf16(a_lo, bh1, acc1, 0, 0, 0);
    }

    // Epilogue: D row = rt*16 + q*4 + reg, col = ct*16 + r; relu + store
    #pragma unroll
    for (int reg = 0; reg < 4; ++reg) {
        int n = n0 + rt * 16 + q * 4 + reg;
        if (n < N_NODES) {
            float v0 = fmaxf(acc0[reg], 0.f);
            float v1 = fmaxf(acc1[reg], 0.f);
            out[(size_t)n * 64 + col0] = v0;
            out[(size_t)n * 64 + col1] = v1;
            if (outb) {
                outb[(size_t)n * 64 + col0] = f2bf_rne(v0);
                outb[(size_t)n * 64 + col1] = f2bf_rne(v1);
            }
        }
    }
}

// ---------------------------------------------------------------------------
// Per-graph readout: batch sorted -> binary-search range, direct reduction,
// fused MLP + softmax. One 256-thread block per graph.
// ---------------------------------------------------------------------------
__global__ __launch_bounds__(256) void readout_kernel(
    const float* __restrict__ x,      // [N,64]
    const int* __restrict__ batch,    // [N], sorted
    const float* __restrict__ Wd1,    // [64][64]
    const float* __restrict__ bd1,    // [64]
    const float* __restrict__ Wd2,    // [64][10]
    const float* __restrict__ bd2,    // [10]
    float* __restrict__ out)          // [256][10]
{
    __shared__ float part[4][64];
    __shared__ float grow[64];
    __shared__ float h1[64];
    __shared__ float logits[NUM_CLASS];

    const int g = blockIdx.x;
    const int tid = threadIdx.x;
    const int d = tid & 63;
    const int r = tid >> 6;   // 0..3

    int lo = 0, hi = N_NODES;
    while (lo < hi) { int mid = (lo + hi) >> 1; if (batch[mid] < g) lo = mid + 1; else hi = mid; }
    const int start = lo;
    hi = N_NODES;
    while (lo < hi) { int mid = (lo + hi) >> 1; if (batch[mid] < g + 1) lo = mid + 1; else hi = mid; }
    const int end = lo;

    float acc = 0.f;
    for (int n = start + r; n < end; n += 4) acc += x[(size_t)n * 64 + d];
    part[r][d] = acc;
    __syncthreads();

    if (tid < 64) {
        grow[d] = part[0][d] + part[1][d] + part[2][d] + part[3][d];
    }
    __syncthreads();

    if (tid < 64) {
        float a = bd1[d];
        #pragma unroll 8
        for (int k = 0; k < 64; ++k) a += grow[k] * Wd1[k * 64 + d];
        h1[d] = fmaxf(a, 0.f);
    }
    __syncthreads();

    if (tid < NUM_CLASS) {
        float a = bd2[tid];
        #pragma unroll 8
        for (int k = 0; k < 64; ++k) a += h1[k] * Wd2[k * 10 + tid];
        logits[tid] = a;
    }
    __syncthreads();

    if (tid < NUM_CLASS) {
        float m = logits[0];
        #pragma unroll
        for (int i = 1; i < NUM_CLASS; ++i) m = fmaxf(m, logits[i]);
        float s = 0.f;
        #pragma unroll
        for (int i = 0; i < NUM_CLASS; ++i) s += expf(logits[i] - m);
        out[g * NUM_CLASS + tid] = expf(logits[tid] - m) / s;
    }
}

extern "C" void kernel_launch(void* const* d_in, const int* in_sizes, int n_in,
                              void* d_out, int out_size, void* d_ws, size_t ws_size,
                              hipStream_t stream) {
    const float* x0   = (const float*)d_in[0];
    const int*   edge = (const int*)d_in[1];
    const int*   batch= (const int*)d_in[2];
    const float* W1   = (const float*)d_in[3];
    const float* b1   = (const float*)d_in[4];
    const float* W2   = (const float*)d_in[5];
    const float* b2   = (const float*)d_in[6];
    const float* Wd1  = (const float*)d_in[7];
    const float* bd1  = (const float*)d_in[8];
    const float* Wd2  = (const float*)d_in[9];
    const float* bd2  = (const float*)d_in[10];
    float* out = (float*)d_out;

    const int* src = edge;             // edge_index[0]
    const int* dst = edge + N_EDGES;   // edge_index[1]

    const size_t nodeBytes = (size_t)N_NODES * DIM * sizeof(float);      // 12.8 MB
    const size_t nodeBytesBf = (size_t)N_NODES * DIM * sizeof(short);    // 6.4 MB
    char* ws = (char*)d_ws;
    float* B   = (float*)ws;            ws += nodeBytes;                 // x1 f32
    float* C   = (float*)ws;            ws += nodeBytes;                 // x2 f32
    int*   deg = (int*)ws;              ws += N_NODES * 4;
    unsigned short* csr = (unsigned short*)ws; ws += (size_t)N_NODES * CAP * 2;
    int*   bcount = (int*)ws;           ws += NB * 4;
    unsigned short* WB = (unsigned short*)ws;  ws += 32768 * 2;          // 64KB packed W1+W2
    unsigned short* Bb = (unsigned short*)ws;  ws += nodeBytesBf;        // x1 bf16
    // Aliases into C (only live BEFORE layer 2 writes C, stream-serial):
    unsigned int*  bdata = (unsigned int*)C;      // bucket data, dead after csr_build
    unsigned short* x0b  = (unsigned short*)C;    // bf16 x0, dead after layer 1

    const int bucketBlocks = (I4_TOTAL + I4_PER_BLOCK - 1) / I4_PER_BLOCK;  // 77
    const int nodeBlocks = (N_NODES + 31) / 32;                              // 1563

    // Bucketed CSR build (by dst) — reused by both layers
    hipMemsetAsync(bcount, 0, NB * sizeof(int), stream);
    bucket_kernel<<<bucketBlocks, 512, 0, stream>>>(
        (const int4*)src, (const int4*)dst, bcount, bdata);
    csr_build_kernel<<<NB, 256, 0, stream>>>(bcount, bdata, deg, csr);

    // bf16 copy of x0 (into C's low 6.4 MB, bdata now dead)
    convert_kernel<<<(N_NODES * 16 + 255) / 256, 256, 0, stream>>>(
        (const float4*)x0, (ushort4*)x0b);

    // Pack W1,W2 into MFMA B-frag layout (hi/lo bf16)
    pack_w_kernel<<<128, 256, 0, stream>>>(W1, W2, WB);

    // Layer 1: gather bf16(x0), self f32, write B f32 + Bb bf16
    sage_layer_kernel<<<nodeBlocks, 256, 0, stream>>>(
        (const float4*)x0, (const ushort4*)x0b, deg, csr, WB, b1, B, Bb);
    // Layer 2: gather Bb, self B, write C f32 only
    sage_layer_kernel<<<nodeBlocks, 256, 0, stream>>>(
        (const float4*)B, (const ushort4*)Bb, deg, csr, WB + 16384, b2, C, nullptr);

    // Readout + MLP + softmax
    readout_kernel<<<NUM_GRAPHS, 256, 0, stream>>>(
        C, batch, Wd1, bd1, Wd2, bd2, out);
}